// Round 16
// baseline (51.051 us; speedup 1.0000x reference)
//
#include <hip/hip_runtime.h>
#include <hip/hip_bf16.h>

// Problem constants
#define IH 4096
#define IW 4096
#define KH 11
#define KW 11
#define OH (IH - KH + 1)   // 4086
#define OW (IW - KW + 1)   // 4086

// Block tile: 64x64 outputs, 4 waves; wave wv -> rows 16wv..16wv+15
#define BM 64
#define BN 64
#define TROWS   74          // staged input rows (64 + 10 halo)
#define TSTRIDE 88          // bf16 row stride: 176 B = 16B-multiple -> aligned
                            // b128 frags; li*44 words mod 32 = 8 residues x2
                            // = free 2-way (m136)
#define NC4     20          // float4 chunks per staged row (80 floats)
#define NCHUNK  (TROWS * NC4)      // 1480
#define NITER   6                  // ceil(1480/256)
#define TILE_SHORTS (TROWS * TSTRIDE)  // 6512

#define TILES_X 64
#define NBLK    1024        // 4 adjacent-x tiles per block

typedef short bf16x4 __attribute__((ext_vector_type(4)));
typedef short bf16x8 __attribute__((ext_vector_type(8)));
typedef float f32x4  __attribute__((ext_vector_type(4)));
typedef int   i32x4  __attribute__((ext_vector_type(4)));

__device__ __forceinline__ short f2b(float f) {
    __hip_bfloat16 h = __float2bfloat16(f);   // RNE
    return __builtin_bit_cast(short, h);
}

// ---- staging split (T14): issue global loads early, LDS-write late ----
__device__ __forceinline__ void stage_load(float4 G[NITER],
                                           const float* __restrict__ x,
                                           int gx0, int gy0, int tid) {
#pragma unroll
    for (int it = 0; it < NITER; ++it) {
        const int i = tid + it * 256;
        float4 v = make_float4(0.f, 0.f, 0.f, 0.f);
        if (i < NCHUNK) {
            const int r  = i / NC4;
            const int c4 = i - r * NC4;
            const int gy = gy0 + r;
            const int gx = gx0 + c4 * 4;
            if (gy < IH && gx + 3 < IW) {
                v = *reinterpret_cast<const float4*>(x + (size_t)gy * IW + gx);
            }
        }
        G[it] = v;
    }
}

__device__ __forceinline__ void stage_write(short* __restrict__ tb,
                                            const float4 G[NITER], int tid) {
#pragma unroll
    for (int it = 0; it < NITER; ++it) {
        const int i = tid + it * 256;
        if (i < NCHUNK) {
            const int r  = i / NC4;
            const int c4 = i - r * NC4;
            bf16x4 b = { f2b(G[it].x), f2b(G[it].y), f2b(G[it].z), f2b(G[it].w) };
            *reinterpret_cast<bf16x4*>(&tb[r * TSTRIDE + c4 * 4]) = b;
        }
    }
}

__device__ __forceinline__ void mfma4(f32x4 acc[4], const i32x4 F[4], bf16x8 b) {
#pragma unroll
    for (int c = 0; c < 4; ++c) {
        acc[c] = __builtin_amdgcn_mfma_f32_16x16x32_bf16(
            __builtin_bit_cast(bf16x8, F[c]), b, acc[c], 0, 0, 0);
    }
}

// ---- per-tile MFMA compute with DPP row-rotation ----
// Math identical to rounds 11-15 (verified): out = sum_kh A_kh * B_kh,
// A_kh[i][k] = X[oy0+kh+i][ox0+k], B_kh[k][j] = w[kh][k-j] (banded).
// At kh->kh+1, lane (g,li) needs exactly lane (g,li+1)'s fragment ->
// DPP row_shl:1 (16-lane rows align with li-groups). Only li=15 needs a
// fresh row (wave-local row 16+kh), whose address is UNIFORM per li-group
// -> broadcast ds_read (~conflict-free). update_dpp(old=fresh, src=F,
// bound_ctrl=0) merges the fresh row into lane 15 (invalid source keeps old).
__device__ __forceinline__ void compute_tile(const short* __restrict__ tb,
                                             const short* __restrict__ bmat,
                                             float bv, float* __restrict__ out,
                                             int gx0, int gy0,
                                             int wv, int g, int li) {
    f32x4 acc[4] = {};
    const short* abase = &tb[(16 * wv + li) * TSTRIDE + g * 8]; // prologue rows
    const short* fbase = &tb[(16 * wv) * TSTRIDE + g * 8];      // fresh rows
    const short* bp    = &bmat[li * 32 + g * 8];

    i32x4 F[4], FR[4];
#pragma unroll
    for (int c = 0; c < 4; ++c)
        F[c] = *reinterpret_cast<const i32x4*>(abase + c * 16);      // kh=0
    bf16x8 Bcur = *reinterpret_cast<const bf16x8*>(bp);
#pragma unroll
    for (int c = 0; c < 4; ++c)                                      // row 16
        FR[c] = *reinterpret_cast<const i32x4*>(fbase + 16 * TSTRIDE + c * 16);
    bf16x8 Bnext = *reinterpret_cast<const bf16x8*>(bp + 512);

#pragma unroll 1
    for (int kh = 0; kh < KH - 1; ++kh) {       // 10 iterations
        mfma4(acc, F, Bcur);                    // compute kh
        // rotate frags to kh+1: lane li takes lane li+1; li=15 takes FR
#pragma unroll
        for (int c = 0; c < 4; ++c) {
#pragma unroll
            for (int d = 0; d < 4; ++d) {
                F[c][d] = __builtin_amdgcn_update_dpp(
                    FR[c][d], F[c][d], 0x101 /*row_shl:1*/, 0xF, 0xF, false);
            }
        }
        // prefetch fresh row for step kh+1 -> kh+2 (clamped; unused if OOB)
        const int nr = (kh + 17 > 25) ? 25 : kh + 17;
#pragma unroll
        for (int c = 0; c < 4; ++c)
            FR[c] = *reinterpret_cast<const i32x4*>(fbase + nr * TSTRIDE + c * 16);
        Bcur = Bnext;
        const int nb = (kh + 2 > 10) ? 10 : kh + 2;
        Bnext = *reinterpret_cast<const bf16x8*>(bp + nb * 512);
    }
    mfma4(acc, F, Bcur);                        // kh = 10

#pragma unroll
    for (int c = 0; c < 4; ++c) {
        const int ox = gx0 + c * 16 + li;
        if (ox < OW) {
#pragma unroll
            for (int r = 0; r < 4; ++r) {
                const int oy = gy0 + wv * 16 + g * 4 + r;
                if (oy < OH) {
                    out[(size_t)oy * OW + ox] = acc[c][r] + bv;
                }
            }
        }
    }
}

// Persistent 4-tile chain with double-buffered input tile (r13/r15 chassis):
//   stage_load(t+1) -> compute(buf[t&1]) -> stage_write(buf[t^1]) -> barrier
__global__ __launch_bounds__(256)
void conv2d_dpp(const float* __restrict__ x,
                const float* __restrict__ w,
                const float* __restrict__ bias,
                float* __restrict__ out) {
    __shared__ short buf[2][TILE_SHORTS];   // 2 x 13024 B
    __shared__ short bmat[KH * 512];        // 11264 B  (total 37312 B)

    const int tid = threadIdx.x;
    // XCD-bijective swizzle (1024 % 8 == 0): each XCD gets 128 contiguous
    // blocks = 8 full tile rows -> x/y halo re-reads hit the same L2.
    const int blk = (blockIdx.x & 7) * (NBLK / 8) + (blockIdx.x >> 3);
    const int t0  = blk * 4;                 // 4 adjacent-x tiles, same row
    const int gy0 = (t0 >> 6) * BM;
    const int gxb = (t0 & (TILES_X - 1)) * BN;

    const int lane = tid & 63;
    const int wv   = tid >> 6;
    const int g    = lane >> 4;
    const int li   = lane & 15;
    const float bv = bias[0];

    // Prologue: stage tile 0 + build B matrices.
    {
        float4 G0[NITER];
        stage_load(G0, x, gxb, gy0, tid);
        stage_write(buf[0], G0, tid);
    }
#pragma unroll
    for (int t = 0; t < 22; ++t) {             // 22*256 = 5632 exact
        const int idx = tid + t * 256;
        const int kh = idx >> 9;
        const int j  = (idx >> 5) & 15;
        const int k  = idx & 31;
        const int d  = k - j;
        const float val = (d >= 0 && d < KW) ? w[kh * KW + d] : 0.f;
        bmat[idx] = f2b(val);
    }
    __syncthreads();

    float4 G[NITER];
#pragma unroll 1
    for (int t = 0; t < 4; ++t) {
        if (t < 3) {
            stage_load(G, x, gxb + (t + 1) * BN, gy0, tid);
            __builtin_amdgcn_sched_barrier(0);   // keep loads above compute
        }
        compute_tile(buf[t & 1], bmat, bv, out, gxb + t * BN, gy0, wv, g, li);
        if (t < 3) {
            stage_write(buf[(t + 1) & 1], G, tid);
            __syncthreads();                     // publish tile t+1
        }
    }
}

extern "C" void kernel_launch(void* const* d_in, const int* in_sizes, int n_in,
                              void* d_out, int out_size, void* d_ws, size_t ws_size,
                              hipStream_t stream) {
    const float* x    = (const float*)d_in[0];
    const float* w    = (const float*)d_in[1];
    const float* bias = (const float*)d_in[2];
    float* out        = (float*)d_out;

    dim3 grid(NBLK);      // 1024 blocks x 4 tiles
    dim3 block(256);
    conv2d_dpp<<<grid, block, 0, stream>>>(x, w, bias, out);
}

// Round 17
// 43.882 us; speedup vs baseline: 1.1634x; 1.1634x over previous
//
#include <hip/hip_runtime.h>
#include <hip/hip_bf16.h>

// Problem constants
#define IH 4096
#define IW 4096
#define KH 11
#define KW 11
#define OH (IH - KH + 1)   // 4086
#define OW (IW - KW + 1)   // 4086

// Block tile: 64x64 outputs, 4 waves; wave wv -> rows 16wv..16wv+15
#define BM 64
#define BN 64
#define TROWS   74          // staged input rows (64 + 10 halo)
#define TSTRIDE 84          // LDS row stride in bf16 (proven ~free conflicts r11-r15)
#define NC4     20          // float4 chunks per staged row (80 floats)
#define NCHUNK  (TROWS * NC4)      // 1480
#define NITER   6                  // ceil(1480/256)
#define TILE_SHORTS (TROWS * TSTRIDE)  // 6216
// LDS total: 2 x 12432 B = 24864 B -> 6 blocks/CU (was 36.4 KB -> 4)

#define TILES_X 64
#define NPAIR   2048        // 2 adjacent-x tiles per block
#define BMAT_SHORTS (KH * 512)     // [11][16][32] bf16 = 5632

typedef short bf16x4 __attribute__((ext_vector_type(4)));
typedef short bf16x8 __attribute__((ext_vector_type(8)));
typedef float f32x4  __attribute__((ext_vector_type(4)));

__device__ __forceinline__ short f2b(float f) {
    __hip_bfloat16 h = __float2bfloat16(f);   // RNE
    return __builtin_bit_cast(short, h);
}

// ---- setup kernel: build banded-Toeplitz B in GLOBAL scratch ----
// B_kh[k][j] = w[kh][k-j] (banded), stored [kh][j][k] so a lane's fragment
// (j=li, k-slice g*8..) is one 16B load. Identical for all blocks -> lives
// in L1/L2, read on the (idle) VMEM pipe instead of the contended LDS pipe.
__global__ void build_bmat(const float* __restrict__ w, short* __restrict__ bm) {
    const int tid = threadIdx.x;
#pragma unroll
    for (int t = 0; t < 22; ++t) {             // 22*256 = 5632 exact
        const int idx = tid + t * 256;
        const int kh = idx >> 9;
        const int j  = (idx >> 5) & 15;
        const int k  = idx & 31;
        const int d  = k - j;
        const float val = (d >= 0 && d < KW) ? w[kh * KW + d] : 0.f;
        bm[idx] = f2b(val);
    }
}

// ---- staging split (T14): issue global loads early, LDS-write late ----
__device__ __forceinline__ void stage_load(float4 G[NITER],
                                           const float* __restrict__ x,
                                           int gx0, int gy0, int tid) {
#pragma unroll
    for (int it = 0; it < NITER; ++it) {
        const int i = tid + it * 256;
        float4 v = make_float4(0.f, 0.f, 0.f, 0.f);
        if (i < NCHUNK) {
            const int r  = i / NC4;
            const int c4 = i - r * NC4;
            const int gy = gy0 + r;
            const int gx = gx0 + c4 * 4;
            if (gy < IH && gx + 3 < IW) {
                v = *reinterpret_cast<const float4*>(x + (size_t)gy * IW + gx);
            }
        }
        G[it] = v;
    }
}

__device__ __forceinline__ void stage_write(short* __restrict__ tb,
                                            const float4 G[NITER], int tid) {
#pragma unroll
    for (int it = 0; it < NITER; ++it) {
        const int i = tid + it * 256;
        if (i < NCHUNK) {
            const int r  = i / NC4;
            const int c4 = i - r * NC4;
            bf16x4 b = { f2b(G[it].x), f2b(G[it].y), f2b(G[it].z), f2b(G[it].w) };
            *reinterpret_cast<bf16x4*>(&tb[r * TSTRIDE + c4 * 4]) = b;
        }
    }
}

// ---- fragment helpers (round-15, verified) ----
__device__ __forceinline__ void loadA(bf16x8 a[4], const short* __restrict__ ap) {
#pragma unroll
    for (int c = 0; c < 4; ++c) {
        bf16x4 lo = *reinterpret_cast<const bf16x4*>(ap + c * 16);
        bf16x4 hi = *reinterpret_cast<const bf16x4*>(ap + c * 16 + 4);
        a[c] = __builtin_shufflevector(lo, hi, 0, 1, 2, 3, 4, 5, 6, 7);
    }
}

__device__ __forceinline__ void mfma4(f32x4 acc[4], const bf16x8 a[4], bf16x8 b) {
#pragma unroll
    for (int c = 0; c < 4; ++c) {
        acc[c] = __builtin_amdgcn_mfma_f32_16x16x32_bf16(a[c], b, acc[c], 0, 0, 0);
    }
}

// ---- per-tile MFMA compute, software-pipelined over kh (round-15 core;
// only change: B fragments come from global bmat instead of LDS) ----
// out[oy0+i][ox0+j] = sum_kh A_kh*B_kh; A_kh[i][k] = X[oy0+kh+i][ox0+k],
// B_kh[k][j] = w[kh][k-j]. A row = lane&15, B col = lane&15,
// C/D col=lane&15,row=(lane>>4)*4+reg.
__device__ __forceinline__ void compute_tile(const short* __restrict__ tb,
                                             const short* __restrict__ bg,
                                             float bv, float* __restrict__ out,
                                             int gx0, int gy0,
                                             int wv, int g, int li) {
    f32x4 acc[4] = {};
    const short* ap = &tb[(16 * wv + li) * TSTRIDE + g * 8];
    const short* bp = &bg[li * 32 + g * 8];

    bf16x8 Ae[4], Ao[4], Be, Bo;
    loadA(Ae, ap);                                        // kh = 0
    Be = *reinterpret_cast<const bf16x8*>(bp);

#pragma unroll 1
    for (int kh2 = 0; kh2 < 5; ++kh2) {
        loadA(Ao, ap + TSTRIDE);                          // kh odd
        Bo = *reinterpret_cast<const bf16x8*>(bp + 512);
        mfma4(acc, Ae, Be);                               // compute even
        ap += 2 * TSTRIDE;
        bp += 1024;
        loadA(Ae, ap);                                    // kh next even
        Be = *reinterpret_cast<const bf16x8*>(bp);
        mfma4(acc, Ao, Bo);                               // compute odd
    }
    mfma4(acc, Ae, Be);                                   // kh = 10

#pragma unroll
    for (int c = 0; c < 4; ++c) {
        const int ox = gx0 + c * 16 + li;
        if (ox < OW) {
#pragma unroll
            for (int r = 0; r < 4; ++r) {
                const int oy = gy0 + wv * 16 + g * 4 + r;
                if (oy < OH) {
                    out[(size_t)oy * OW + ox] = acc[c][r] + bv;
                }
            }
        }
    }
}

// Persistent 2-tile chain, double-buffered input tile. Grid 2048 so the
// 6-blocks/CU LDS capacity is actually demanded (r15's grid 1024 = 4/CU
// could never use more).
__global__ __launch_bounds__(256)
void conv2d_g(const float* __restrict__ x,
              const short* __restrict__ bg,
              const float* __restrict__ bias,
              float* __restrict__ out) {
    __shared__ short buf[2][TILE_SHORTS];   // 24864 B total

    const int tid = threadIdx.x;
    // XCD-bijective swizzle (2048 % 8 == 0).
    const int pair = (blockIdx.x & 7) * (NPAIR / 8) + (blockIdx.x >> 3);
    const int t0   = pair * 2;               // even -> t0,t0+1 share a row
    const int gy0  = (t0 >> 6) * BM;
    const int gxb  = (t0 & (TILES_X - 1)) * BN;

    const int lane = tid & 63;
    const int wv   = tid >> 6;
    const int g    = lane >> 4;
    const int li   = lane & 15;
    const float bv = bias[0];

    // Stage tile 0.
    {
        float4 G0[NITER];
        stage_load(G0, x, gxb, gy0, tid);
        stage_write(buf[0], G0, tid);
    }
    __syncthreads();

    // T14: issue tile 1's loads before tile 0's compute.
    float4 G[NITER];
    stage_load(G, x, gxb + BN, gy0, tid);
    __builtin_amdgcn_sched_barrier(0);       // keep loads above compute

    compute_tile(buf[0], bg, bv, out, gxb, gy0, wv, g, li);

    stage_write(buf[1], G, tid);
    __syncthreads();                         // publish tile 1

    compute_tile(buf[1], bg, bv, out, gxb + BN, gy0, wv, g, li);
}

extern "C" void kernel_launch(void* const* d_in, const int* in_sizes, int n_in,
                              void* d_out, int out_size, void* d_ws, size_t ws_size,
                              hipStream_t stream) {
    const float* x    = (const float*)d_in[0];
    const float* w    = (const float*)d_in[1];
    const float* bias = (const float*)d_in[2];
    float* out        = (float*)d_out;
    short* bm         = (short*)d_ws;        // 11264 B of scratch

    build_bmat<<<dim3(1), dim3(256), 0, stream>>>(w, bm);

    dim3 grid(NPAIR);     // 2048 blocks x 2 tiles
    dim3 block(256);
    conv2d_g<<<grid, block, 0, stream>>>(x, bm, bias, out);
}

// Round 18
// 38.794 us; speedup vs baseline: 1.3159x; 1.1311x over previous
//
#include <hip/hip_runtime.h>
#include <hip/hip_bf16.h>

// Problem constants
#define IH 4096
#define IW 4096
#define KH 11
#define KW 11
#define OH (IH - KH + 1)   // 4086
#define OW (IW - KW + 1)   // 4086

// Block tile: 64x64 outputs, 4 waves; wave wv -> rows 16wv..16wv+15
#define BM 64
#define BN 64
#define TROWS   74          // staged input rows (64 + 10 halo)
#define TSTRIDE 84          // LDS row stride in bf16 (proven ~free conflicts r11-r15)
#define NC4     20          // float4 chunks per staged row (80 floats)
#define NCHUNK  (TROWS * NC4)      // 1480
#define NITER   6                  // ceil(1480/256)
#define TILE_SHORTS (TROWS * TSTRIDE)  // 6216
#define BMAT_SHORTS (KH * 512)         // [11][16][32] bf16 = 5632
// LDS total: (6216 + 5632) * 2 = 23696 B -> 6 blocks/CU

#define TILES_X 64
#define NTILE   4096

typedef short bf16x4 __attribute__((ext_vector_type(4)));
typedef short bf16x8 __attribute__((ext_vector_type(8)));
typedef float f32x4  __attribute__((ext_vector_type(4)));

__device__ __forceinline__ short f2b(float f) {
    __hip_bfloat16 h = __float2bfloat16(f);   // RNE
    return __builtin_bit_cast(short, h);
}

// ---- setup kernel (r17): banded-Toeplitz B in global scratch, bf16 ----
// B_kh[k][j] = w[kh][k-j] (banded), stored [kh][j][k] so a lane's fragment
// (j=li, k-slice g*8..) is one contiguous 16B chunk.
__global__ void build_bmat(const float* __restrict__ w, short* __restrict__ bm) {
    const int tid = threadIdx.x;
#pragma unroll
    for (int t = 0; t < 22; ++t) {             // 22*256 = 5632 exact
        const int idx = tid + t * 256;
        const int kh = idx >> 9;
        const int j  = (idx >> 5) & 15;
        const int k  = idx & 31;
        const int d  = k - j;
        const float val = (d >= 0 && d < KW) ? w[kh * KW + d] : 0.f;
        bm[idx] = f2b(val);
    }
}

// ---- fragment helpers (rounds 15/17, verified) ----
__device__ __forceinline__ void loadA(bf16x8 a[4], const short* __restrict__ ap) {
#pragma unroll
    for (int c = 0; c < 4; ++c) {
        bf16x4 lo = *reinterpret_cast<const bf16x4*>(ap + c * 16);
        bf16x4 hi = *reinterpret_cast<const bf16x4*>(ap + c * 16 + 4);
        a[c] = __builtin_shufflevector(lo, hi, 0, 1, 2, 3, 4, 5, 6, 7);
    }
}

__device__ __forceinline__ void mfma4(f32x4 acc[4], const bf16x8 a[4], bf16x8 b) {
#pragma unroll
    for (int c = 0; c < 4; ++c) {
        acc[c] = __builtin_amdgcn_mfma_f32_16x16x32_bf16(a[c], b, acc[c], 0, 0, 0);
    }
}

// Single-tile block, max-TLP structure:
//   stage (sync) + copy B -> one barrier -> pipelined compute -> store.
// No chains, no dbuf, no early-issued staging (r17 lesson: early staging
// loads sit ahead of in-compute loads in the vmcnt queue and turn every
// B-frag wait into a full HBM-latency stall). All in-compute loads are LDS.
// 23.7 KB LDS + ~56 VGPR -> 6 blocks/CU; staggered blocks cover staging.
__global__ __launch_bounds__(256)
void conv2d_tlp(const float* __restrict__ x,
                const short* __restrict__ bg,
                const float* __restrict__ bias,
                float* __restrict__ out) {
    __shared__ short lds[TILE_SHORTS + BMAT_SHORTS];   // 23696 B

    const int tid = threadIdx.x;
    // XCD-bijective swizzle (4096 % 8 == 0): each XCD gets 512 contiguous
    // tiles = 8 full tile rows -> halo re-reads hit the same L2.
    const int blk = (blockIdx.x & 7) * (NTILE / 8) + (blockIdx.x >> 3);
    const int gy0 = (blk >> 6) * BM;
    const int gx0 = (blk & (TILES_X - 1)) * BN;

    const int lane = tid & 63;
    const int wv   = tid >> 6;
    const int g    = lane >> 4;
    const int li   = lane & 15;
    const float bv = bias[0];

    // ---- Stage input tile (sync: load -> cvt -> ds_write) ----
#pragma unroll
    for (int it = 0; it < NITER; ++it) {
        const int i = tid + it * 256;
        if (i < NCHUNK) {
            const int r  = i / NC4;
            const int c4 = i - r * NC4;
            const int gy = gy0 + r;
            const int gx = gx0 + c4 * 4;
            float4 v = make_float4(0.f, 0.f, 0.f, 0.f);
            if (gy < IH && gx + 3 < IW) {
                v = *reinterpret_cast<const float4*>(x + (size_t)gy * IW + gx);
            }
            bf16x4 b = { f2b(v.x), f2b(v.y), f2b(v.z), f2b(v.w) };
            *reinterpret_cast<bf16x4*>(&lds[r * TSTRIDE + c4 * 4]) = b;
        }
    }
    // ---- Copy B matrices from global scratch (L2-hot, 16B chunks) ----
#pragma unroll
    for (int t = 0; t < 3; ++t) {              // 704 int4 chunks
        const int idx = tid + t * 256;
        if (idx < (BMAT_SHORTS * 2) / 16) {
            reinterpret_cast<int4*>(&lds[TILE_SHORTS])[idx] =
                reinterpret_cast<const int4*>(bg)[idx];
        }
    }
    __syncthreads();

    // ---- Pipelined MFMA compute (r15 core, verified) ----
    // out[oy0+i][ox0+j] = sum_kh A_kh*B_kh; A_kh[i][k] = X[oy0+kh+i][ox0+k],
    // B_kh[k][j] = w[kh][k-j]. A row = lane&15, B col = lane&15,
    // C/D col=lane&15,row=(lane>>4)*4+reg.
    f32x4 acc[4] = {};
    const short* ap = &lds[(16 * wv + li) * TSTRIDE + g * 8];
    const short* bp = &lds[TILE_SHORTS + li * 32 + g * 8];

    bf16x8 Ae[4], Ao[4], Be, Bo;
    loadA(Ae, ap);                                        // kh = 0
    Be = *reinterpret_cast<const bf16x8*>(bp);

#pragma unroll 1
    for (int kh2 = 0; kh2 < 5; ++kh2) {
        loadA(Ao, ap + TSTRIDE);                          // kh odd
        Bo = *reinterpret_cast<const bf16x8*>(bp + 512);
        mfma4(acc, Ae, Be);                               // compute even
        ap += 2 * TSTRIDE;
        bp += 1024;
        loadA(Ae, ap);                                    // kh next even
        Be = *reinterpret_cast<const bf16x8*>(bp);
        mfma4(acc, Ao, Bo);                               // compute odd
    }
    mfma4(acc, Ae, Be);                                   // kh = 10

    // ---- Write back ----
#pragma unroll
    for (int c = 0; c < 4; ++c) {
        const int ox = gx0 + c * 16 + li;
        if (ox < OW) {
#pragma unroll
            for (int r = 0; r < 4; ++r) {
                const int oy = gy0 + wv * 16 + g * 4 + r;
                if (oy < OH) {
                    out[(size_t)oy * OW + ox] = acc[c][r] + bv;
                }
            }
        }
    }
}

extern "C" void kernel_launch(void* const* d_in, const int* in_sizes, int n_in,
                              void* d_out, int out_size, void* d_ws, size_t ws_size,
                              hipStream_t stream) {
    const float* x    = (const float*)d_in[0];
    const float* w    = (const float*)d_in[1];
    const float* bias = (const float*)d_in[2];
    float* out        = (float*)d_out;
    short* bm         = (short*)d_ws;        // 11264 B of scratch

    build_bmat<<<dim3(1), dim3(256), 0, stream>>>(w, bm);

    dim3 grid(NTILE);     // 4096 single-tile blocks
    dim3 block(256);
    conv2d_tlp<<<grid, block, 0, stream>>>(x, bm, bias, out);
}